// Round 4
// baseline (294.785 us; speedup 1.0000x reference)
//
#include <hip/hip_runtime.h>

// ---------------- problem constants ----------------
#define NN   10000     // nodes
#define E0   160000    // raw edges
#define ET   170000    // edges + self loops
#define DIN  165       // input channels
#define KP   192       // DIN padded to 32x for MFMA K-loop
#define HID  1024      // 8 heads * 128
#define NH   8
#define BP   200       // LDS row pitch for gemm1 B-tile (conflict-free, 16B-aligned rows)
#define K2P  1032      // LDS row pitch for gemm2 B
#define YT   2         // gemm1: n-tiles per block (A regs reused YT times)

// dtypes (settled r6): ALL float tensors f32, edge_index int32, OUTPUT f32.

typedef __bf16 bf16x8 __attribute__((ext_vector_type(8)));
typedef float  f32x4  __attribute__((ext_vector_type(4)));
typedef float  f32x2  __attribute__((ext_vector_type(2)));

__device__ __forceinline__ float bf2f(unsigned short u) {
    unsigned int i = ((unsigned int)u) << 16;
    return __builtin_bit_cast(float, i);
}
__device__ __forceinline__ unsigned short f2bf(float f) {
    unsigned int i = __builtin_bit_cast(unsigned int, f);
    i += 0x7fffu + ((i >> 16) & 1u);   // round-to-nearest-even
    return (unsigned short)(i >> 16);
}
__device__ __forceinline__ float fin(float x) {
    return fminf(fmaxf(x, -1e30f), 1e30f);
}
__device__ __forceinline__ int clampi(int s) {
    return min(max(s, 0), NN - 1);
}
__device__ __forceinline__ void unpack8(uint4 u, float* f) {
    f[0]=bf2f((unsigned short)(u.x)); f[1]=bf2f((unsigned short)(u.x>>16));
    f[2]=bf2f((unsigned short)(u.y)); f[3]=bf2f((unsigned short)(u.y>>16));
    f[4]=bf2f((unsigned short)(u.z)); f[5]=bf2f((unsigned short)(u.z>>16));
    f[6]=bf2f((unsigned short)(u.w)); f[7]=bf2f((unsigned short)(u.w>>16));
}
// one packed u32 (2 bf16) -> f32x2 in 2 VALU ops (lshl / and)
__device__ __forceinline__ f32x2 up2(unsigned int u) {
    f32x2 r;
    r.x = __builtin_bit_cast(float, u << 16);
    r.y = __builtin_bit_cast(float, u & 0xffff0000u);
    return r;
}

// ---------------- debug ----------------
__global__ __launch_bounds__(256) void debug_fill(float* __restrict__ out, float val) {
    int i = blockIdx.x * 256 + threadIdx.x;
    if (i < NN) out[i] = val;
}

// ---------------- FUSED A: bn1_stats (125 blocks) + edge_hist (665 blocks) ------
// Independent latency-bound kernels; fused so their tails overlap on one dispatch.
__global__ __launch_bounds__(256) void fuseA_kernel(const float* __restrict__ x,
                                                    float* __restrict__ colsum, float* __restrict__ colsq,
                                                    const int* __restrict__ ei, int* __restrict__ deg) {
    const int b = blockIdx.x;
    if (b < 125) {
        // bn1_stats: 125 blocks x 80 rows, 4-way split accumulators
        int c = threadIdx.x;
        if (c >= DIN) return;
        int r0 = b * 80;
        float a0=0,a1=0,a2=0,a3=0, q0=0,q1=0,q2=0,q3=0;
        for (int r = r0; r < r0 + 80; r += 4) {
            float v0 = x[(size_t)r * DIN + c];
            float v1 = x[(size_t)(r + 1) * DIN + c];
            float v2 = x[(size_t)(r + 2) * DIN + c];
            float v3 = x[(size_t)(r + 3) * DIN + c];
            a0 += v0; q0 += v0 * v0;
            a1 += v1; q1 += v1 * v1;
            a2 += v2; q2 += v2 * v2;
            a3 += v3; q3 += v3 * v3;
        }
        atomicAdd(&colsum[c], (a0 + a1) + (a2 + a3));
        atomicAdd(&colsq[c],  (q0 + q1) + (q2 + q3));
    } else {
        // edge_hist
        int e = (b - 125) * 256 + threadIdx.x;
        if (e >= ET) return;
        int d = (e < E0) ? ei[E0 + e] : (e - E0);
        atomicAdd(&deg[clampi(d)], 1);
    }
}

// ---------------- FUSED B: scan (block 0, 1024 thr) + bn1_apply (blocks>=1) -----
__global__ __launch_bounds__(1024) void fuseB_kernel(
    const int* __restrict__ deg,
    int* __restrict__ offs, int* __restrict__ cur, int* __restrict__ perm,
    const float* __restrict__ x,
    const float* __restrict__ colsum, const float* __restrict__ colsq,
    const float* __restrict__ gamma, const float* __restrict__ beta,
    unsigned short* __restrict__ hn) {
    if (blockIdx.x != 0) {
        // bn1_apply at 1024 threads/block
        int idx = (blockIdx.x - 1) * 1024 + threadIdx.x;
        if (idx >= NN * KP) return;
        int r = idx / KP, c = idx - r * KP;
        float v = 0.f;
        if (c < DIN) {
            float mu  = colsum[c] * (1.f / NN);
            float var = fmaxf(colsq[c] * (1.f / NN) - mu * mu, 0.f);
            float a = gamma[c] * rsqrtf(var + 1e-5f);
            float b = beta[c] - mu * a;
            v = fin(x[(size_t)r * DIN + c] * a + b);
        }
        hn[idx] = f2bf(v);
        return;
    }
    // ---- scan + degree-descending perm (single block, 1024 threads) ----
    __shared__ int wsum[16];
    __shared__ int bins[64];
    __shared__ int bcur[64];
    const int tid = threadIdx.x;
    const int base = tid * 10;
    int loc[10];
    int run = 0;
    #pragma unroll
    for (int j = 0; j < 10; ++j) {
        int idx = base + j;
        int v = (idx < NN) ? deg[idx] : 0;
        loc[j] = run;
        run += v;
    }
    const int lane = tid & 63;
    const int w = tid >> 6;
    int inc = run;
    #pragma unroll
    for (int s = 1; s < 64; s <<= 1) {
        int t = __shfl_up(inc, s);
        if (lane >= s) inc += t;
    }
    if (lane == 63) wsum[w] = inc;
    if (tid < 64) bins[tid] = 0;
    __syncthreads();
    int woff = 0;
    #pragma unroll
    for (int k = 0; k < 16; ++k) woff += (k < w) ? wsum[k] : 0;
    const int toff = woff + inc - run;
    #pragma unroll
    for (int j = 0; j < 10; ++j) {
        int idx = base + j;
        if (idx < NN) {
            int e = toff + loc[j]; offs[idx] = e; cur[idx] = e;
            atomicAdd(&bins[63 - min(deg[idx], 63)], 1);   // descending-degree bucket
        }
    }
    if (tid == 1023) offs[NN] = woff + inc;
    __syncthreads();
    if (tid < 64) {   // wave 0: exclusive scan of 64 bins
        int v = bins[tid];
        int binc = v;
        #pragma unroll
        for (int s = 1; s < 64; s <<= 1) {
            int t = __shfl_up(binc, s);
            if (tid >= s) binc += t;
        }
        bcur[tid] = binc - v;
    }
    __syncthreads();
    #pragma unroll
    for (int j = 0; j < 10; ++j) {
        int idx = base + j;
        if (idx < NN) {
            int pos = atomicAdd(&bcur[63 - min(deg[idx], 63)], 1);
            perm[pos] = idx;
        }
    }
}

// ---------------- FUSED C: w1_transpose (192 blocks) + edge_scatter (665) -------
__global__ __launch_bounds__(256) void fuseC_kernel(const float* __restrict__ wl,
                                                    const float* __restrict__ wr,
                                                    unsigned short* __restrict__ wlt,
                                                    unsigned short* __restrict__ wrt,
                                                    const int* __restrict__ ei,
                                                    int* __restrict__ cur, int* __restrict__ ssrc) {
    const int b = blockIdx.x;
    if (b < 192) {
        // w1_transpose: b -> (kx 0..5, ky 0..15, z 0..1)
        const int z  = b / 96;
        const int rm = b - z * 96;
        const int ky = rm / 6;
        const int kx = rm - ky * 6;
        const float* src    = z ? wr  : wl;
        unsigned short* dst = z ? wrt : wlt;
        __shared__ float ts[32][65];
        const int k0 = kx * 32;
        const int n0 = ky * 64;
        const int tid = threadIdx.x;
        for (int idx = tid; idx < 32 * 64; idx += 256) {
            int k = idx >> 6, n = idx & 63;
            ts[k][n] = (k0 + k < DIN) ? src[(size_t)(k0 + k) * HID + n0 + n] : 0.f;
        }
        __syncthreads();
        for (int idx = tid; idx < 64 * 32; idx += 256) {
            int n = idx >> 5, k = idx & 31;
            dst[(size_t)(n0 + n) * KP + k0 + k] = f2bf(ts[k][n]);
        }
    } else {
        // edge_scatter
        int e = (b - 192) * 256 + threadIdx.x;
        if (e >= ET) return;
        int s, d;
        if (e < E0) { s = ei[e]; d = ei[E0 + e]; }
        else        { s = e - E0; d = e - E0; }
        int pos = atomicAdd(&cur[clampi(d)], 1);
        if (pos >= 0 && pos < ET) ssrc[pos] = clampi(s);
    }
}

// ---------------- GEMM1 (r19: A-in-registers, YT n-tiles per block) -------------
// r1 counters: dur 53us = hbm_bytes/1.6TB/s, MfmaUtil 5%, VALUBusy 18%, occ 26%
// -> issue-rate/latency-bound, not BW-saturated. Fix: hoist all 12 A-loads into
// regs explicitly (48 VGPR), reuse across YT=2 n-tiles (grid 79x8): 2x MFMA per
// sync-region, A latency amortized, hn L2 traffic halved.
__global__ __launch_bounds__(256) void gemm1_kernel(
    const unsigned short* __restrict__ hn,
    const unsigned short* __restrict__ wlt,  // [HID][KP] bf16
    const unsigned short* __restrict__ wrt,
    const float* __restrict__ bl,
    const float* __restrict__ br,
    unsigned short* __restrict__ xl,
    unsigned short* __restrict__ xr) {
    __shared__ unsigned short bs[2][64 * BP];   // 51.2 KB (B-tiles, then C staging)
    const int tid  = threadIdx.x;
    const int lane = tid & 63;
    const int wave = tid >> 6;
    const int col  = lane & 15;
    const int q    = lane >> 4;

    const int mbase = blockIdx.x * 128 + wave * 32;
    const int am0 = mbase + col;
    const int am1 = am0 + 16;
    const bool aok0 = (am0 < NN), aok1 = (am1 < NN);

    // ---- A fragments: loaded ONCE, reused for all YT n-tiles ----
    bf16x8 A0[6], A1[6];
    #pragma unroll
    for (int kt = 0; kt < 6; ++kt) {
        const int kk = kt * 32 + q * 8;
        uint4 a0u = make_uint4(0u,0u,0u,0u), a1u = make_uint4(0u,0u,0u,0u);
        if (aok0) a0u = *(const uint4*)(hn + (size_t)am0 * KP + kk);
        if (aok1) a1u = *(const uint4*)(hn + (size_t)am1 * KP + kk);
        A0[kt] = __builtin_bit_cast(bf16x8, a0u);
        A1[kt] = __builtin_bit_cast(bf16x8, a1u);
    }

    const int mblk = blockIdx.x * 128;

    #pragma unroll
    for (int yt = 0; yt < YT; ++yt) {
        const int n0 = (blockIdx.y * YT + yt) * 64;
        if (yt) __syncthreads();                 // prior epilogue LDS reads done

        // stage both B-tiles: coalesced uint2 reads, contiguous LDS writes
        for (int idx = tid; idx < 64 * 48 * 2; idx += 256) {
            int z = idx >= 64 * 48;
            int rem = z ? idx - 64 * 48 : idx;
            int r = rem / 48, c = rem - r * 48;
            const unsigned short* wt = z ? wrt : wlt;
            uint2 v = *(const uint2*)(wt + (size_t)(n0 + r) * KP + c * 4);
            *(uint2*)&bs[z][r * BP + c * 4] = v;
        }
        __syncthreads();

        f32x4 accL[2][4], accR[2][4];
        #pragma unroll
        for (int m = 0; m < 2; ++m)
            for (int nt = 0; nt < 4; ++nt)
                for (int r = 0; r < 4; ++r) { accL[m][nt][r] = 0.f; accR[m][nt][r] = 0.f; }

        #pragma unroll
        for (int kt = 0; kt < 6; ++kt) {
            const int kk = kt * 32 + q * 8;
            #pragma unroll
            for (int nt = 0; nt < 4; ++nt) {
                bf16x8 bfl = __builtin_bit_cast(bf16x8, *(const uint4*)&bs[0][(nt * 16 + col) * BP + kk]);
                accL[0][nt] = __builtin_amdgcn_mfma_f32_16x16x32_bf16(A0[kt], bfl, accL[0][nt], 0, 0, 0);
                accL[1][nt] = __builtin_amdgcn_mfma_f32_16x16x32_bf16(A1[kt], bfl, accL[1][nt], 0, 0, 0);
                bf16x8 bfr = __builtin_bit_cast(bf16x8, *(const uint4*)&bs[1][(nt * 16 + col) * BP + kk]);
                accR[0][nt] = __builtin_amdgcn_mfma_f32_16x16x32_bf16(A0[kt], bfr, accR[0][nt], 0, 0, 0);
                accR[1][nt] = __builtin_amdgcn_mfma_f32_16x16x32_bf16(A1[kt], bfr, accR[1][nt], 0, 0, 0);
            }
        }

        // ---- epilogue: bias + fin -> LDS bf16 [128][72] x2, full-line stores ----
        __syncthreads();                         // all B reads done; reuse bs
        unsigned short* cl = &bs[0][0];          // pitch 72 shorts = 144 B
        unsigned short* cr = cl + 128 * 72;      // 18432 shorts <= 25600 avail
        #pragma unroll
        for (int nt = 0; nt < 4; ++nt) {
            const int nc = n0 + nt * 16 + col;
            const float bLv = bl[nc];
            const float bRv = br[nc];
            #pragma unroll
            for (int m = 0; m < 2; ++m) {
                #pragma unroll
                for (int r = 0; r < 4; ++r) {
                    const int lrow = wave * 32 + m * 16 + q * 4 + r;
                    cl[lrow * 72 + nt * 16 + col] = f2bf(fin(accL[m][nt][r] + bLv));
                    cr[lrow * 72 + nt * 16 + col] = f2bf(fin(accR[m][nt][r] + bRv));
                }
            }
        }
        __syncthreads();
        for (int t = tid; t < 128 * 8; t += 256) {   // 8 uint4 per row (64 cols)
            const int row = t >> 3, ch = t & 7;
            const int grow = mblk + row;
            if (grow < NN) {
                *(uint4*)(xl + (size_t)grow * HID + n0 + ch * 8) = *(const uint4*)&cl[row * 72 + ch * 8];
                *(uint4*)(xr + (size_t)grow * HID + n0 + ch * 8) = *(const uint4*)&cr[row * 72 + ch * 8];
            }
        }
    }
}

// ---------------- GAT1 wave-per-node: r15 skeleton + f32x2 packed math ----------
// r19: channel math on f32x2 (v_pk_add/mul/fma_f32 eligible), ~96->~64 math ops
// per edge-lane. Loop structure EXACTLY r15 (compiler pipelines it better than
// the r16 manual rotation). Alias (agg=xr1) safe by program order within wave.
__global__ __launch_bounds__(256) void gat1_node(
    const unsigned short* __restrict__ xl1, const unsigned short* xr1,
    const float* __restrict__ att1, const float* __restrict__ bias1,
    const int* __restrict__ offs, const int* __restrict__ ssrc,
    const int* __restrict__ perm,
    unsigned short* agg) {
    const int lane = threadIdx.x & 63;
    const int wave = threadIdx.x >> 6;
    const int i = perm[blockIdx.x * 4 + wave];   // degree-descending
    const int e0 = offs[i];
    const int e1 = max(offs[i + 1], e0);

    f32x2 xr2[8], at2[8], o2[8];
    {
        const uint4* xp = (const uint4*)(xr1 + (size_t)i * HID + lane * 16);
        uint4 u0 = xp[0], u1 = xp[1];
        unsigned int w[8] = {u0.x, u0.y, u0.z, u0.w, u1.x, u1.y, u1.z, u1.w};
        const float4* ap = (const float4*)(att1 + lane * 16);
        float4 a0 = ap[0], a1 = ap[1], a2 = ap[2], a3 = ap[3];
        float af[16] = {a0.x,a0.y,a0.z,a0.w, a1.x,a1.y,a1.z,a1.w,
                        a2.x,a2.y,a2.z,a2.w, a3.x,a3.y,a3.z,a3.w};
        #pragma unroll
        for (int j = 0; j < 8; ++j) {
            xr2[j] = up2(w[j]);
            at2[j].x = af[2*j]; at2[j].y = af[2*j+1];
            o2[j].x = 0.f; o2[j].y = 0.f;
        }
    }
    float s = 0.f;

    int e = e0;
    for (; e + 1 < e1; e += 2) {
        const int s0i = clampi(ssrc[e]);
        const int s1i = clampi(ssrc[e + 1]);
        const uint4* xp0 = (const uint4*)(xl1 + (size_t)s0i * HID + lane * 16);
        const uint4* xp1 = (const uint4*)(xl1 + (size_t)s1i * HID + lane * 16);
        uint4 a0 = xp0[0], a1 = xp0[1], b0 = xp1[0], b1 = xp1[1];
        unsigned int wa[8] = {a0.x,a0.y,a0.z,a0.w, a1.x,a1.y,a1.z,a1.w};
        unsigned int wb[8] = {b0.x,b0.y,b0.z,b0.w, b1.x,b1.y,b1.z,b1.w};
        f32x2 xa[8], xb[8];
        #pragma unroll
        for (int j = 0; j < 8; ++j) { xa[j] = up2(wa[j]); xb[j] = up2(wb[j]); }
        f32x2 pa = {0.f, 0.f}, pb = {0.f, 0.f};
        #pragma unroll
        for (int j = 0; j < 8; ++j) {
            f32x2 va = xa[j] + xr2[j];
            f32x2 vb = xb[j] + xr2[j];
            va = __builtin_elementwise_max(va, 0.2f * va);
            vb = __builtin_elementwise_max(vb, 0.2f * vb);
            pa = __builtin_elementwise_fma(at2[j], va, pa);
            pb = __builtin_elementwise_fma(at2[j], vb, pb);
        }
        float p0 = pa.x + pa.y;
        float p1 = pb.x + pb.y;
        p0 += __shfl_xor(p0, 1); p0 += __shfl_xor(p0, 2); p0 += __shfl_xor(p0, 4);
        p1 += __shfl_xor(p1, 1); p1 += __shfl_xor(p1, 2); p1 += __shfl_xor(p1, 4);
        const float aa0 = __expf(fminf(fin(p0), 50.f));
        const float aa1 = __expf(fminf(fin(p1), 50.f));
        s += aa0 + aa1;
        f32x2 av0; av0.x = aa0; av0.y = aa0;
        f32x2 av1; av1.x = aa1; av1.y = aa1;
        #pragma unroll
        for (int j = 0; j < 8; ++j)
            o2[j] = __builtin_elementwise_fma(av0, xa[j],
                    __builtin_elementwise_fma(av1, xb[j], o2[j]));
    }
    if (e < e1) {
        const int sidx = clampi(ssrc[e]);
        const uint4* xp = (const uint4*)(xl1 + (size_t)sidx * HID + lane * 16);
        uint4 u0 = xp[0], u1 = xp[1];
        unsigned int w[8] = {u0.x,u0.y,u0.z,u0.w, u1.x,u1.y,u1.z,u1.w};
        f32x2 xv[8];
        #pragma unroll
        for (int j = 0; j < 8; ++j) xv[j] = up2(w[j]);
        f32x2 p2 = {0.f, 0.f};
        #pragma unroll
        for (int j = 0; j < 8; ++j) {
            f32x2 v = xv[j] + xr2[j];
            v = __builtin_elementwise_max(v, 0.2f * v);
            p2 = __builtin_elementwise_fma(at2[j], v, p2);
        }
        float p = p2.x + p2.y;
        p += __shfl_xor(p, 1); p += __shfl_xor(p, 2); p += __shfl_xor(p, 4);
        const float a = __expf(fminf(fin(p), 50.f));
        s += a;
        f32x2 av; av.x = a; av.y = a;
        #pragma unroll
        for (int j = 0; j < 8; ++j)
            o2[j] = __builtin_elementwise_fma(av, xv[j], o2[j]);
    }

    const float inv = 1.f / (s + 1e-16f);
    const float4* bp = (const float4*)(bias1 + lane * 16);
    float4 b0 = bp[0], b1 = bp[1], b2 = bp[2], b3 = bp[3];
    float bb[16] = {b0.x,b0.y,b0.z,b0.w, b1.x,b1.y,b1.z,b1.w,
                    b2.x,b2.y,b2.z,b2.w, b3.x,b3.y,b3.z,b3.w};
    unsigned short ov[16];
    #pragma unroll
    for (int j = 0; j < 8; ++j) {
        ov[2*j]   = f2bf(fin(o2[j].x * inv + bb[2*j]));
        ov[2*j+1] = f2bf(fin(o2[j].y * inv + bb[2*j+1]));
    }
    uint4* op = (uint4*)(agg + (size_t)i * HID + lane * 16);
    op[0] = *(const uint4*)&ov[0];
    op[1] = *(const uint4*)&ov[8];
}

// ---------------- BN2 stats over agg [NN,HID] bf16 ----------------
__global__ __launch_bounds__(256) void bn2_stats(const unsigned short* __restrict__ agg,
                                                 float* __restrict__ colsum, float* __restrict__ colsq) {
    int r0 = blockIdx.x * 80;
    int t = threadIdx.x;
    float s0=0,s1=0,s2=0,s3=0,q0=0,q1=0,q2=0,q3=0;
    #pragma unroll 2
    for (int r = r0; r < r0 + 80; ++r) {
        const ushort4 u = *(const ushort4*)(agg + (size_t)r * HID + t * 4);
        float v0=bf2f(u.x), v1=bf2f(u.y), v2=bf2f(u.z), v3=bf2f(u.w);
        s0+=v0; q0+=v0*v0; s1+=v1; q1+=v1*v1;
        s2+=v2; q2+=v2*v2; s3+=v3; q3+=v3*v3;
    }
    atomicAdd(&colsum[t*4+0], s0); atomicAdd(&colsq[t*4+0], q0);
    atomicAdd(&colsum[t*4+1], s1); atomicAdd(&colsq[t*4+1], q1);
    atomicAdd(&colsum[t*4+2], s2); atomicAdd(&colsq[t*4+2], q2);
    atomicAdd(&colsum[t*4+3], s3); atomicAdd(&colsq[t*4+3], q3);
}

// ---------------- GEMM2 (K split across 4 waves + LDS reduce; grid 625) ----
__global__ __launch_bounds__(256) void gemm2_kernel(
    const unsigned short* __restrict__ agg,
    const float* __restrict__ colsum, const float* __restrict__ colsq,
    const float* __restrict__ gamma, const float* __restrict__ beta,
    const float* __restrict__ wl2, const float* __restrict__ wr2,
    const float* __restrict__ bl2, const float* __restrict__ br2,
    float* __restrict__ xl2, float* __restrict__ xr2) {
    __shared__ unsigned short bs[16 * K2P];   // 33 KB
    __shared__ float a2s[HID], b2s[HID];      // 8 KB affine table
    __shared__ float red[4 * 64 * 4];         // 4 KB wave partials
    const int tid  = threadIdx.x;
    const int lane = tid & 63;
    const int wave = tid >> 6;
    const int col  = lane & 15;
    const int q    = lane >> 4;

    for (int idx = tid; idx < 16 * HID; idx += 256) {
        int n = idx >> 10, k = idx & (HID - 1);
        float v = (n < 8) ? wl2[k * 8 + n] : wr2[k * 8 + (n - 8)];
        bs[n * K2P + k] = f2bf(v);
    }
    for (int cc = tid; cc < HID; cc += 256) {
        float mu  = colsum[cc] * (1.f / NN);
        float var = fmaxf(colsq[cc] * (1.f / NN) - mu * mu, 0.f);
        float a = gamma[cc] * rsqrtf(var + 1e-5f);
        a2s[cc] = a; b2s[cc] = beta[cc] - mu * a;
    }
    __syncthreads();

    const int m0 = blockIdx.x * 16;
    const int am = m0 + col;

    f32x4 acc;
    acc[0] = acc[1] = acc[2] = acc[3] = 0.f;
    #pragma unroll
    for (int t = 0; t < 8; ++t) {
        const int kt = wave * 8 + t;          // K-split: wave w owns kt in [8w, 8w+8)
        const int kk = kt * 32 + q * 8;
        uint4 u = *(const uint4*)(agg + (size_t)am * HID + kk);
        float xv[8];
        unpack8(u, xv);
        unsigned short hv[8];
        #pragma unroll
        for (int j = 0; j < 8; ++j) {
            float v = xv[j] * a2s[kk + j] + b2s[kk + j];
            v = fmaxf(v, 0.01f * v);          // leaky 0.01
            hv[j] = f2bf(fin(v));
        }
        bf16x8 af = __builtin_bit_cast(bf16x8, *(const uint4*)hv);
        bf16x8 bf = __builtin_bit_cast(bf16x8, *(const uint4*)&bs[col * K2P + kk]);
        acc = __builtin_amdgcn_mfma_f32_16x16x32_bf16(af, bf, acc, 0, 0, 0);
    }

    *(f32x4*)&red[(wave * 64 + lane) * 4] = acc;
    __syncthreads();
    if (wave == 0) {
        f32x4 a0 = *(const f32x4*)&red[lane * 4];
        f32x4 a1 = *(const f32x4*)&red[(64 + lane) * 4];
        f32x4 a2 = *(const f32x4*)&red[(128 + lane) * 4];
        f32x4 a3 = *(const f32x4*)&red[(192 + lane) * 4];
        acc = (a0 + a1) + (a2 + a3);
        const float bv = (col < 8) ? bl2[col] : br2[col - 8];
        float* outp = (col < 8) ? (xl2 + col) : (xr2 + (col - 8));
        #pragma unroll
        for (int r = 0; r < 4; ++r) {
            const int row = m0 + q * 4 + r;
            outp[row * 8] = fin(acc[r] + bv);
        }
    }
}

// ---------------- GAT2 single-pass (degree-sorted order) ----------------
__global__ __launch_bounds__(256) void gat2_node(
    const float* __restrict__ xl2, const float* __restrict__ xr2,
    const float* __restrict__ att2, const float* __restrict__ bias2,
    const int* __restrict__ offs, const int* __restrict__ ssrc,
    const int* __restrict__ perm,
    float* __restrict__ out) {
    const int lane = threadIdx.x & 63;
    const int wave = threadIdx.x >> 6;
    const int i = perm[blockIdx.x * 4 + wave];
    const int h = lane & 7, slot = lane >> 3;
    const int e0 = offs[i];
    const int e1 = max(offs[i + 1], e0);
    const float xr_h = xr2[i * 8 + h];
    const float att_h = att2[h];
    float ssum = 0.f, wsum = 0.f;
    for (int eb = e0; eb < e1; eb += 8) {
        int e = eb + slot;
        if (e < e1) {
            float xlv = xl2[clampi(ssrc[e]) * 8 + h];
            float v = xlv + xr_h;
            v = fmaxf(v, 0.2f * v);
            float a = __expf(fminf(fin(att_h * v), 50.f));
            ssum += a; wsum += a * xlv;
        }
    }
    ssum += __shfl_xor(ssum, 8); ssum += __shfl_xor(ssum, 16); ssum += __shfl_xor(ssum, 32);
    wsum += __shfl_xor(wsum, 8); wsum += __shfl_xor(wsum, 16); wsum += __shfl_xor(wsum, 32);
    float v = fin(wsum / (ssum + 1e-16f));
    v += __shfl_xor(v, 1); v += __shfl_xor(v, 2); v += __shfl_xor(v, 4);
    if (lane == 0) out[i] = fin(v * 0.125f + bias2[0]);
}

// ---------------- launch ----------------
extern "C" void kernel_launch(void* const* d_in, const int* in_sizes, int n_in,
                              void* d_out, int out_size, void* d_ws, size_t ws_size,
                              hipStream_t stream) {
    float* out = (float*)d_out;   // reference output dtype is float32

    static const int expected[18] = {
        NN * DIN, DIN, DIN, DIN * HID, HID, DIN * HID, HID, HID, HID,
        HID, HID, HID * NH, NH, HID * NH, NH, NH, 1, 2 * E0
    };
    if (n_in != 18) {
        debug_fill<<<(NN + 255) / 256, 256, 0, stream>>>(out, 8192.f + 64.f * (float)n_in);
        return;
    }
    for (int i = 0; i < 18; ++i) {
        if (in_sizes[i] != expected[i]) {
            debug_fill<<<(NN + 255) / 256, 256, 0, stream>>>(out, 4096.f + 32.f * (float)i);
            return;
        }
    }

    const float* x      = (const float*)d_in[0];
    const float* gamma1 = (const float*)d_in[1];
    const float* beta1  = (const float*)d_in[2];
    const float* Wl1    = (const float*)d_in[3];
    const float* bl1    = (const float*)d_in[4];
    const float* Wr1    = (const float*)d_in[5];
    const float* br1    = (const float*)d_in[6];
    const float* att1   = (const float*)d_in[7];
    const float* bias1  = (const float*)d_in[8];
    const float* gamma2 = (const float*)d_in[9];
    const float* beta2  = (const float*)d_in[10];
    const float* Wl2    = (const float*)d_in[11];
    const float* bl2    = (const float*)d_in[12];
    const float* Wr2    = (const float*)d_in[13];
    const float* br2    = (const float*)d_in[14];
    const float* att2   = (const float*)d_in[15];
    const float* bias2  = (const float*)d_in[16];
    const int*   ei     = (const int*)d_in[17];

    char* p = (char*)d_ws;
    auto alloc = [&](size_t bytes) -> void* {
        void* r = (void*)p;
        p += (bytes + 255) & ~(size_t)255;
        return r;
    };
    unsigned short* xl1  = (unsigned short*)alloc((size_t)NN * HID * 2);  // 20.48 MB
    unsigned short* xr1  = (unsigned short*)alloc((size_t)NN * HID * 2);  // 20.48 MB
    unsigned short* agg  = xr1;                                           // ALIAS (see gat1_node)
    unsigned short* hn   = (unsigned short*)alloc((size_t)NN * KP * 2);   // 3.84 MB
    unsigned short* wlt  = (unsigned short*)alloc((size_t)HID * KP * 2);  // 0.39 MB
    unsigned short* wrt  = (unsigned short*)alloc((size_t)HID * KP * 2);  // 0.39 MB
    float*          xl2  = (float*)alloc((size_t)NN * 8 * 4);
    float*          xr2  = (float*)alloc((size_t)NN * 8 * 4);
    int*            offs = (int*)alloc((NN + 1) * 4);
    int*            cur  = (int*)alloc(NN * 4);
    int*            ssrc = (int*)alloc(ET * 4);
    int*            perm = (int*)alloc(NN * 4);
    char* zbase = p;
    float* colsum1 = (float*)alloc(DIN * 4);
    float* colsq1  = (float*)alloc(DIN * 4);
    float* colsum2 = (float*)alloc(HID * 4);
    float* colsq2  = (float*)alloc(HID * 4);
    int*   deg     = (int*)alloc(NN * 4);
    size_t zlen = (size_t)(p - zbase);
    hipMemsetAsync(zbase, 0, zlen, stream);

    // 9 dispatches (r19: horizontal fusion of small kernels; gemm1 A-in-regs;
    // gat1 f32x2 packed math)
    fuseA_kernel<<<125 + (ET + 255) / 256, 256, 0, stream>>>(x, colsum1, colsq1, ei, deg);
    fuseB_kernel<<<1 + (NN * KP + 1023) / 1024, 1024, 0, stream>>>(
        deg, offs, cur, perm, x, colsum1, colsq1, gamma1, beta1, hn);
    fuseC_kernel<<<192 + (ET + 255) / 256, 256, 0, stream>>>(Wl1, Wr1, wlt, wrt, ei, cur, ssrc);
    gemm1_kernel<<<dim3((NN + 127) / 128, HID / 64 / YT), 256, 0, stream>>>(
        hn, wlt, wrt, bl1, br1, xl1, xr1);
    gat1_node<<<NN / 4, 256, 0, stream>>>(xl1, xr1, att1, bias1, offs, ssrc, perm, agg);
    bn2_stats<<<125, 256, 0, stream>>>(agg, colsum2, colsq2);
    gemm2_kernel<<<NN / 16, 256, 0, stream>>>(agg, colsum2, colsq2, gamma2, beta2,
                                              Wl2, Wr2, bl2, br2, xl2, xr2);
    gat2_node<<<NN / 4, 256, 0, stream>>>(xl2, xr2, att2, bias2, offs, ssrc, perm, out);
}

// Round 5
// 275.297 us; speedup vs baseline: 1.0708x; 1.0708x over previous
//
#include <hip/hip_runtime.h>

// ---------------- problem constants ----------------
#define NN   10000     // nodes
#define E0   160000    // raw edges
#define ET   170000    // edges + self loops
#define DIN  165       // input channels
#define KP   192       // DIN padded to 32x for MFMA K-loop
#define HID  1024      // 8 heads * 128
#define NH   8
#define AP   200       // gemm1 A-tile LDS pitch (shorts): 2-way banks only, 16B rows
#define CP   136       // gemm1 C-stage LDS pitch (shorts)
#define K2P  1032      // LDS row pitch for gemm2 B

// dtypes (settled r6): ALL float tensors f32, edge_index int32, OUTPUT f32.

typedef __bf16 bf16x8 __attribute__((ext_vector_type(8)));
typedef float  f32x4  __attribute__((ext_vector_type(4)));
typedef float  f32x2  __attribute__((ext_vector_type(2)));

__device__ __forceinline__ float bf2f(unsigned short u) {
    unsigned int i = ((unsigned int)u) << 16;
    return __builtin_bit_cast(float, i);
}
__device__ __forceinline__ unsigned short f2bf(float f) {
    unsigned int i = __builtin_bit_cast(unsigned int, f);
    i += 0x7fffu + ((i >> 16) & 1u);   // round-to-nearest-even
    return (unsigned short)(i >> 16);
}
__device__ __forceinline__ float fin(float x) {
    return fminf(fmaxf(x, -1e30f), 1e30f);
}
__device__ __forceinline__ int clampi(int s) {
    return min(max(s, 0), NN - 1);
}
__device__ __forceinline__ void unpack8(uint4 u, float* f) {
    f[0]=bf2f((unsigned short)(u.x)); f[1]=bf2f((unsigned short)(u.x>>16));
    f[2]=bf2f((unsigned short)(u.y)); f[3]=bf2f((unsigned short)(u.y>>16));
    f[4]=bf2f((unsigned short)(u.z)); f[5]=bf2f((unsigned short)(u.z>>16));
    f[6]=bf2f((unsigned short)(u.w)); f[7]=bf2f((unsigned short)(u.w>>16));
}
// one packed u32 (2 bf16) -> f32x2 in 2 VALU ops (lshl / and)
__device__ __forceinline__ f32x2 up2(unsigned int u) {
    f32x2 r;
    r.x = __builtin_bit_cast(float, u << 16);
    r.y = __builtin_bit_cast(float, u & 0xffff0000u);
    return r;
}

// ---------------- debug ----------------
__global__ __launch_bounds__(256) void debug_fill(float* __restrict__ out, float val) {
    int i = blockIdx.x * 256 + threadIdx.x;
    if (i < NN) out[i] = val;
}

// ---------------- FUSED A: bn1_stats (125 blocks) + edge_hist (665 blocks) ------
__global__ __launch_bounds__(256) void fuseA_kernel(const float* __restrict__ x,
                                                    float* __restrict__ colsum, float* __restrict__ colsq,
                                                    const int* __restrict__ ei, int* __restrict__ deg) {
    const int b = blockIdx.x;
    if (b < 125) {
        int c = threadIdx.x;
        if (c >= DIN) return;
        int r0 = b * 80;
        float a0=0,a1=0,a2=0,a3=0, q0=0,q1=0,q2=0,q3=0;
        for (int r = r0; r < r0 + 80; r += 4) {
            float v0 = x[(size_t)r * DIN + c];
            float v1 = x[(size_t)(r + 1) * DIN + c];
            float v2 = x[(size_t)(r + 2) * DIN + c];
            float v3 = x[(size_t)(r + 3) * DIN + c];
            a0 += v0; q0 += v0 * v0;
            a1 += v1; q1 += v1 * v1;
            a2 += v2; q2 += v2 * v2;
            a3 += v3; q3 += v3 * v3;
        }
        atomicAdd(&colsum[c], (a0 + a1) + (a2 + a3));
        atomicAdd(&colsq[c],  (q0 + q1) + (q2 + q3));
    } else {
        int e = (b - 125) * 256 + threadIdx.x;
        if (e >= ET) return;
        int d = (e < E0) ? ei[E0 + e] : (e - E0);
        atomicAdd(&deg[clampi(d)], 1);
    }
}

// ---------------- FUSED B: scan (block 0, 1024 thr) + bn1_apply (blocks>=1) -----
__global__ __launch_bounds__(1024) void fuseB_kernel(
    const int* __restrict__ deg,
    int* __restrict__ offs, int* __restrict__ cur, int* __restrict__ perm,
    const float* __restrict__ x,
    const float* __restrict__ colsum, const float* __restrict__ colsq,
    const float* __restrict__ gamma, const float* __restrict__ beta,
    unsigned short* __restrict__ hn) {
    if (blockIdx.x != 0) {
        int idx = (blockIdx.x - 1) * 1024 + threadIdx.x;
        if (idx >= NN * KP) return;
        int r = idx / KP, c = idx - r * KP;
        float v = 0.f;
        if (c < DIN) {
            float mu  = colsum[c] * (1.f / NN);
            float var = fmaxf(colsq[c] * (1.f / NN) - mu * mu, 0.f);
            float a = gamma[c] * rsqrtf(var + 1e-5f);
            float b = beta[c] - mu * a;
            v = fin(x[(size_t)r * DIN + c] * a + b);
        }
        hn[idx] = f2bf(v);
        return;
    }
    __shared__ int wsum[16];
    __shared__ int bins[64];
    __shared__ int bcur[64];
    const int tid = threadIdx.x;
    const int base = tid * 10;
    int loc[10];
    int run = 0;
    #pragma unroll
    for (int j = 0; j < 10; ++j) {
        int idx = base + j;
        int v = (idx < NN) ? deg[idx] : 0;
        loc[j] = run;
        run += v;
    }
    const int lane = tid & 63;
    const int w = tid >> 6;
    int inc = run;
    #pragma unroll
    for (int s = 1; s < 64; s <<= 1) {
        int t = __shfl_up(inc, s);
        if (lane >= s) inc += t;
    }
    if (lane == 63) wsum[w] = inc;
    if (tid < 64) bins[tid] = 0;
    __syncthreads();
    int woff = 0;
    #pragma unroll
    for (int k = 0; k < 16; ++k) woff += (k < w) ? wsum[k] : 0;
    const int toff = woff + inc - run;
    #pragma unroll
    for (int j = 0; j < 10; ++j) {
        int idx = base + j;
        if (idx < NN) {
            int e = toff + loc[j]; offs[idx] = e; cur[idx] = e;
            atomicAdd(&bins[63 - min(deg[idx], 63)], 1);   // descending-degree bucket
        }
    }
    if (tid == 1023) offs[NN] = woff + inc;
    __syncthreads();
    if (tid < 64) {   // wave 0: exclusive scan of 64 bins
        int v = bins[tid];
        int binc = v;
        #pragma unroll
        for (int s = 1; s < 64; s <<= 1) {
            int t = __shfl_up(binc, s);
            if (tid >= s) binc += t;
        }
        bcur[tid] = binc - v;
    }
    __syncthreads();
    #pragma unroll
    for (int j = 0; j < 10; ++j) {
        int idx = base + j;
        if (idx < NN) {
            int pos = atomicAdd(&bcur[63 - min(deg[idx], 63)], 1);
            perm[pos] = idx;
        }
    }
}

// ---------------- FUSED C: w1_transpose (192 blocks) + edge_scatter (665) -------
__global__ __launch_bounds__(256) void fuseC_kernel(const float* __restrict__ wl,
                                                    const float* __restrict__ wr,
                                                    unsigned short* __restrict__ wlt,
                                                    unsigned short* __restrict__ wrt,
                                                    const int* __restrict__ ei,
                                                    int* __restrict__ cur, int* __restrict__ ssrc) {
    const int b = blockIdx.x;
    if (b < 192) {
        const int z  = b / 96;
        const int rm = b - z * 96;
        const int ky = rm / 6;
        const int kx = rm - ky * 6;
        const float* src    = z ? wr  : wl;
        unsigned short* dst = z ? wrt : wlt;
        __shared__ float ts[32][65];
        const int k0 = kx * 32;
        const int n0 = ky * 64;
        const int tid = threadIdx.x;
        for (int idx = tid; idx < 32 * 64; idx += 256) {
            int k = idx >> 6, n = idx & 63;
            ts[k][n] = (k0 + k < DIN) ? src[(size_t)(k0 + k) * HID + n0 + n] : 0.f;
        }
        __syncthreads();
        for (int idx = tid; idx < 64 * 32; idx += 256) {
            int n = idx >> 5, k = idx & 31;
            dst[(size_t)(n0 + n) * KP + k0 + k] = f2bf(ts[k][n]);
        }
    } else {
        int e = (b - 192) * 256 + threadIdx.x;
        if (e >= ET) return;
        int s, d;
        if (e < E0) { s = ei[e]; d = ei[E0 + e]; }
        else        { s = e - E0; d = e - E0; }
        int pos = atomicAdd(&cur[clampi(d)], 1);
        if (pos >= 0 && pos < ET) ssrc[pos] = clampi(s);
    }
}

// ---------------- GEMM1 r20: 64x128 tiles, B-in-regs, batched A staging ---------
// r19 post-mortem: dur invariant 53us across 3 structures; MfmaUtil 5%, VALU 15%,
// occ 13% -> latency-serialized staging + too few blocks. Now: grid 157x16=2512
// blocks (6 resident/CU by 25.6KB LDS), B' = concat(L,R) cols so each block does
// one output tile; A staged ONCE via 6 batched loads->6 LDS writes; 2 syncs/block.
__global__ __launch_bounds__(256) void gemm1_kernel(
    const unsigned short* __restrict__ hn,
    const unsigned short* __restrict__ wlt,  // [HID][KP] bf16
    const unsigned short* __restrict__ wrt,
    const float* __restrict__ bl,
    const float* __restrict__ br,
    unsigned short* __restrict__ xl,
    unsigned short* __restrict__ xr) {
    __shared__ unsigned short as[64 * AP];   // 25.6 KB: A-tile, then C staging
    const int tid  = threadIdx.x;
    const int lane = tid & 63;
    const int wave = tid >> 6;
    const int col  = lane & 15;
    const int q    = lane >> 4;

    const int m0 = blockIdx.x * 64;
    const int z  = blockIdx.y >> 3;            // 0 = L half, 1 = R half
    const int nb = (blockIdx.y & 7) * 128;     // col base within that half
    const unsigned short* wt = z ? wrt : wlt;

    // ---- B fragments: 12 batched uint4 loads (L2-resident W'), held in regs ----
    bf16x8 B[2][6];
    {
        const int bc0 = nb + wave * 32 + col;
        #pragma unroll
        for (int nt = 0; nt < 2; ++nt) {
            const unsigned short* wp = wt + (size_t)(bc0 + nt * 16) * KP + q * 8;
            #pragma unroll
            for (int kt = 0; kt < 6; ++kt)
                B[nt][kt] = __builtin_bit_cast(bf16x8, *(const uint4*)(wp + kt * 32));
        }
    }

    // ---- A-tile staging: 6 batched global loads -> 6 LDS writes ----
    {
        const int r  = tid >> 2;               // 0..63
        const int s0 = (tid & 3) * 48;         // short offset within row
        const int grow = m0 + r;
        uint4 t0 = {0,0,0,0}, t1 = t0, t2 = t0, t3 = t0, t4 = t0, t5 = t0;
        if (grow < NN) {
            const unsigned short* gp = hn + (size_t)grow * KP + s0;
            t0 = *(const uint4*)(gp);
            t1 = *(const uint4*)(gp + 8);
            t2 = *(const uint4*)(gp + 16);
            t3 = *(const uint4*)(gp + 24);
            t4 = *(const uint4*)(gp + 32);
            t5 = *(const uint4*)(gp + 40);
        }
        unsigned short* lp = as + r * AP + s0;
        *(uint4*)(lp)      = t0;
        *(uint4*)(lp + 8)  = t1;
        *(uint4*)(lp + 16) = t2;
        *(uint4*)(lp + 24) = t3;
        *(uint4*)(lp + 32) = t4;
        *(uint4*)(lp + 40) = t5;
    }
    __syncthreads();

    // ---- MFMA: 4 m-tiles x 2 n-tiles x 6 k = 48 per wave ----
    f32x4 acc[4][2];
    #pragma unroll
    for (int mi = 0; mi < 4; ++mi)
        for (int nt = 0; nt < 2; ++nt)
            acc[mi][nt][0] = acc[mi][nt][1] = acc[mi][nt][2] = acc[mi][nt][3] = 0.f;

    #pragma unroll
    for (int kt = 0; kt < 6; ++kt) {
        const int kk = kt * 32 + q * 8;
        bf16x8 A[4];
        #pragma unroll
        for (int mi = 0; mi < 4; ++mi)
            A[mi] = __builtin_bit_cast(bf16x8, *(const uint4*)(as + (mi * 16 + col) * AP + kk));
        #pragma unroll
        for (int mi = 0; mi < 4; ++mi) {
            acc[mi][0] = __builtin_amdgcn_mfma_f32_16x16x32_bf16(A[mi], B[0][kt], acc[mi][0], 0, 0, 0);
            acc[mi][1] = __builtin_amdgcn_mfma_f32_16x16x32_bf16(A[mi], B[1][kt], acc[mi][1], 0, 0, 0);
        }
    }

    // ---- epilogue: bias + fin -> LDS C [64][CP], then full 256B-row stores ----
    __syncthreads();                            // A reads done; reuse as[] for C
    #pragma unroll
    for (int nt = 0; nt < 2; ++nt) {
        const int lc = wave * 32 + nt * 16 + col;   // 0..127
        const float bv = (z ? br : bl)[nb + lc];
        #pragma unroll
        for (int mi = 0; mi < 4; ++mi) {
            #pragma unroll
            for (int r = 0; r < 4; ++r) {
                const int lr = mi * 16 + q * 4 + r;
                as[lr * CP + lc] = f2bf(fin(acc[mi][nt][r] + bv));
            }
        }
    }
    __syncthreads();
    {
        const int r  = tid >> 2;               // 0..63
        const int sg = (tid & 3) * 32;         // 32-col (64B) segment
        const int grow = m0 + r;
        if (grow < NN) {
            unsigned short* dst = (z ? xr : xl) + (size_t)grow * HID + nb + sg;
            const unsigned short* sp = as + r * CP + sg;
            *(uint4*)(dst)      = *(const uint4*)(sp);
            *(uint4*)(dst + 8)  = *(const uint4*)(sp + 8);
            *(uint4*)(dst + 16) = *(const uint4*)(sp + 16);
            *(uint4*)(dst + 24) = *(const uint4*)(sp + 24);
        }
    }
}

// ---------------- GAT1 wave-per-node: r15 skeleton + f32x2 packed math ----------
__global__ __launch_bounds__(256) void gat1_node(
    const unsigned short* __restrict__ xl1, const unsigned short* xr1,
    const float* __restrict__ att1, const float* __restrict__ bias1,
    const int* __restrict__ offs, const int* __restrict__ ssrc,
    const int* __restrict__ perm,
    unsigned short* agg) {
    const int lane = threadIdx.x & 63;
    const int wave = threadIdx.x >> 6;
    const int i = perm[blockIdx.x * 4 + wave];   // degree-descending
    const int e0 = offs[i];
    const int e1 = max(offs[i + 1], e0);

    f32x2 xr2[8], at2[8], o2[8];
    {
        const uint4* xp = (const uint4*)(xr1 + (size_t)i * HID + lane * 16);
        uint4 u0 = xp[0], u1 = xp[1];
        unsigned int w[8] = {u0.x, u0.y, u0.z, u0.w, u1.x, u1.y, u1.z, u1.w};
        const float4* ap = (const float4*)(att1 + lane * 16);
        float4 a0 = ap[0], a1 = ap[1], a2 = ap[2], a3 = ap[3];
        float af[16] = {a0.x,a0.y,a0.z,a0.w, a1.x,a1.y,a1.z,a1.w,
                        a2.x,a2.y,a2.z,a2.w, a3.x,a3.y,a3.z,a3.w};
        #pragma unroll
        for (int j = 0; j < 8; ++j) {
            xr2[j] = up2(w[j]);
            at2[j].x = af[2*j]; at2[j].y = af[2*j+1];
            o2[j].x = 0.f; o2[j].y = 0.f;
        }
    }
    float s = 0.f;

    int e = e0;
    for (; e + 1 < e1; e += 2) {
        const int s0i = clampi(ssrc[e]);
        const int s1i = clampi(ssrc[e + 1]);
        const uint4* xp0 = (const uint4*)(xl1 + (size_t)s0i * HID + lane * 16);
        const uint4* xp1 = (const uint4*)(xl1 + (size_t)s1i * HID + lane * 16);
        uint4 a0 = xp0[0], a1 = xp0[1], b0 = xp1[0], b1 = xp1[1];
        unsigned int wa[8] = {a0.x,a0.y,a0.z,a0.w, a1.x,a1.y,a1.z,a1.w};
        unsigned int wb[8] = {b0.x,b0.y,b0.z,b0.w, b1.x,b1.y,b1.z,b1.w};
        f32x2 xa[8], xb[8];
        #pragma unroll
        for (int j = 0; j < 8; ++j) { xa[j] = up2(wa[j]); xb[j] = up2(wb[j]); }
        f32x2 pa = {0.f, 0.f}, pb = {0.f, 0.f};
        #pragma unroll
        for (int j = 0; j < 8; ++j) {
            f32x2 va = xa[j] + xr2[j];
            f32x2 vb = xb[j] + xr2[j];
            va = __builtin_elementwise_max(va, 0.2f * va);
            vb = __builtin_elementwise_max(vb, 0.2f * vb);
            pa = __builtin_elementwise_fma(at2[j], va, pa);
            pb = __builtin_elementwise_fma(at2[j], vb, pb);
        }
        float p0 = pa.x + pa.y;
        float p1 = pb.x + pb.y;
        p0 += __shfl_xor(p0, 1); p0 += __shfl_xor(p0, 2); p0 += __shfl_xor(p0, 4);
        p1 += __shfl_xor(p1, 1); p1 += __shfl_xor(p1, 2); p1 += __shfl_xor(p1, 4);
        const float aa0 = __expf(fminf(fin(p0), 50.f));
        const float aa1 = __expf(fminf(fin(p1), 50.f));
        s += aa0 + aa1;
        f32x2 av0; av0.x = aa0; av0.y = aa0;
        f32x2 av1; av1.x = aa1; av1.y = aa1;
        #pragma unroll
        for (int j = 0; j < 8; ++j)
            o2[j] = __builtin_elementwise_fma(av0, xa[j],
                    __builtin_elementwise_fma(av1, xb[j], o2[j]));
    }
    if (e < e1) {
        const int sidx = clampi(ssrc[e]);
        const uint4* xp = (const uint4*)(xl1 + (size_t)sidx * HID + lane * 16);
        uint4 u0 = xp[0], u1 = xp[1];
        unsigned int w[8] = {u0.x,u0.y,u0.z,u0.w, u1.x,u1.y,u1.z,u1.w};
        f32x2 xv[8];
        #pragma unroll
        for (int j = 0; j < 8; ++j) xv[j] = up2(w[j]);
        f32x2 p2 = {0.f, 0.f};
        #pragma unroll
        for (int j = 0; j < 8; ++j) {
            f32x2 v = xv[j] + xr2[j];
            v = __builtin_elementwise_max(v, 0.2f * v);
            p2 = __builtin_elementwise_fma(at2[j], v, p2);
        }
        float p = p2.x + p2.y;
        p += __shfl_xor(p, 1); p += __shfl_xor(p, 2); p += __shfl_xor(p, 4);
        const float a = __expf(fminf(fin(p), 50.f));
        s += a;
        f32x2 av; av.x = a; av.y = a;
        #pragma unroll
        for (int j = 0; j < 8; ++j)
            o2[j] = __builtin_elementwise_fma(av, xv[j], o2[j]);
    }

    const float inv = 1.f / (s + 1e-16f);
    const float4* bp = (const float4*)(bias1 + lane * 16);
    float4 b0 = bp[0], b1 = bp[1], b2 = bp[2], b3 = bp[3];
    float bb[16] = {b0.x,b0.y,b0.z,b0.w, b1.x,b1.y,b1.z,b1.w,
                    b2.x,b2.y,b2.z,b2.w, b3.x,b3.y,b3.z,b3.w};
    unsigned short ov[16];
    #pragma unroll
    for (int j = 0; j < 8; ++j) {
        ov[2*j]   = f2bf(fin(o2[j].x * inv + bb[2*j]));
        ov[2*j+1] = f2bf(fin(o2[j].y * inv + bb[2*j+1]));
    }
    uint4* op = (uint4*)(agg + (size_t)i * HID + lane * 16);
    op[0] = *(const uint4*)&ov[0];
    op[1] = *(const uint4*)&ov[8];
}

// ---------------- BN2 stats over agg [NN,HID] bf16 ----------------
__global__ __launch_bounds__(256) void bn2_stats(const unsigned short* __restrict__ agg,
                                                 float* __restrict__ colsum, float* __restrict__ colsq) {
    int r0 = blockIdx.x * 80;
    int t = threadIdx.x;
    float s0=0,s1=0,s2=0,s3=0,q0=0,q1=0,q2=0,q3=0;
    #pragma unroll 2
    for (int r = r0; r < r0 + 80; ++r) {
        const ushort4 u = *(const ushort4*)(agg + (size_t)r * HID + t * 4);
        float v0=bf2f(u.x), v1=bf2f(u.y), v2=bf2f(u.z), v3=bf2f(u.w);
        s0+=v0; q0+=v0*v0; s1+=v1; q1+=v1*v1;
        s2+=v2; q2+=v2*v2; s3+=v3; q3+=v3*v3;
    }
    atomicAdd(&colsum[t*4+0], s0); atomicAdd(&colsq[t*4+0], q0);
    atomicAdd(&colsum[t*4+1], s1); atomicAdd(&colsq[t*4+1], q1);
    atomicAdd(&colsum[t*4+2], s2); atomicAdd(&colsq[t*4+2], q2);
    atomicAdd(&colsum[t*4+3], s3); atomicAdd(&colsq[t*4+3], q3);
}

// ---------------- GEMM2 (K split across 4 waves + LDS reduce; grid 625) ----
__global__ __launch_bounds__(256) void gemm2_kernel(
    const unsigned short* __restrict__ agg,
    const float* __restrict__ colsum, const float* __restrict__ colsq,
    const float* __restrict__ gamma, const float* __restrict__ beta,
    const float* __restrict__ wl2, const float* __restrict__ wr2,
    const float* __restrict__ bl2, const float* __restrict__ br2,
    float* __restrict__ xl2, float* __restrict__ xr2) {
    __shared__ unsigned short bs[16 * K2P];   // 33 KB
    __shared__ float a2s[HID], b2s[HID];      // 8 KB affine table
    __shared__ float red[4 * 64 * 4];         // 4 KB wave partials
    const int tid  = threadIdx.x;
    const int lane = tid & 63;
    const int wave = tid >> 6;
    const int col  = lane & 15;
    const int q    = lane >> 4;

    for (int idx = tid; idx < 16 * HID; idx += 256) {
        int n = idx >> 10, k = idx & (HID - 1);
        float v = (n < 8) ? wl2[k * 8 + n] : wr2[k * 8 + (n - 8)];
        bs[n * K2P + k] = f2bf(v);
    }
    for (int cc = tid; cc < HID; cc += 256) {
        float mu  = colsum[cc] * (1.f / NN);
        float var = fmaxf(colsq[cc] * (1.f / NN) - mu * mu, 0.f);
        float a = gamma[cc] * rsqrtf(var + 1e-5f);
        a2s[cc] = a; b2s[cc] = beta[cc] - mu * a;
    }
    __syncthreads();

    const int m0 = blockIdx.x * 16;
    const int am = m0 + col;

    f32x4 acc;
    acc[0] = acc[1] = acc[2] = acc[3] = 0.f;
    #pragma unroll
    for (int t = 0; t < 8; ++t) {
        const int kt = wave * 8 + t;          // K-split: wave w owns kt in [8w, 8w+8)
        const int kk = kt * 32 + q * 8;
        uint4 u = *(const uint4*)(agg + (size_t)am * HID + kk);
        float xv[8];
        unpack8(u, xv);
        unsigned short hv[8];
        #pragma unroll
        for (int j = 0; j < 8; ++j) {
            float v = xv[j] * a2s[kk + j] + b2s[kk + j];
            v = fmaxf(v, 0.01f * v);          // leaky 0.01
            hv[j] = f2bf(fin(v));
        }
        bf16x8 af = __builtin_bit_cast(bf16x8, *(const uint4*)hv);
        bf16x8 bf = __builtin_bit_cast(bf16x8, *(const uint4*)&bs[col * K2P + kk]);
        acc = __builtin_amdgcn_mfma_f32_16x16x32_bf16(af, bf, acc, 0, 0, 0);
    }

    *(f32x4*)&red[(wave * 64 + lane) * 4] = acc;
    __syncthreads();
    if (wave == 0) {
        f32x4 a0 = *(const f32x4*)&red[lane * 4];
        f32x4 a1 = *(const f32x4*)&red[(64 + lane) * 4];
        f32x4 a2 = *(const f32x4*)&red[(128 + lane) * 4];
        f32x4 a3 = *(const f32x4*)&red[(192 + lane) * 4];
        acc = (a0 + a1) + (a2 + a3);
        const float bv = (col < 8) ? bl2[col] : br2[col - 8];
        float* outp = (col < 8) ? (xl2 + col) : (xr2 + (col - 8));
        #pragma unroll
        for (int r = 0; r < 4; ++r) {
            const int row = m0 + q * 4 + r;
            outp[row * 8] = fin(acc[r] + bv);
        }
    }
}

// ---------------- GAT2 single-pass (degree-sorted order) ----------------
__global__ __launch_bounds__(256) void gat2_node(
    const float* __restrict__ xl2, const float* __restrict__ xr2,
    const float* __restrict__ att2, const float* __restrict__ bias2,
    const int* __restrict__ offs, const int* __restrict__ ssrc,
    const int* __restrict__ perm,
    float* __restrict__ out) {
    const int lane = threadIdx.x & 63;
    const int wave = threadIdx.x >> 6;
    const int i = perm[blockIdx.x * 4 + wave];
    const int h = lane & 7, slot = lane >> 3;
    const int e0 = offs[i];
    const int e1 = max(offs[i + 1], e0);
    const float xr_h = xr2[i * 8 + h];
    const float att_h = att2[h];
    float ssum = 0.f, wsum = 0.f;
    for (int eb = e0; eb < e1; eb += 8) {
        int e = eb + slot;
        if (e < e1) {
            float xlv = xl2[clampi(ssrc[e]) * 8 + h];
            float v = xlv + xr_h;
            v = fmaxf(v, 0.2f * v);
            float a = __expf(fminf(fin(att_h * v), 50.f));
            ssum += a; wsum += a * xlv;
        }
    }
    ssum += __shfl_xor(ssum, 8); ssum += __shfl_xor(ssum, 16); ssum += __shfl_xor(ssum, 32);
    wsum += __shfl_xor(wsum, 8); wsum += __shfl_xor(wsum, 16); wsum += __shfl_xor(wsum, 32);
    float v = fin(wsum / (ssum + 1e-16f));
    v += __shfl_xor(v, 1); v += __shfl_xor(v, 2); v += __shfl_xor(v, 4);
    if (lane == 0) out[i] = fin(v * 0.125f + bias2[0]);
}

// ---------------- launch ----------------
extern "C" void kernel_launch(void* const* d_in, const int* in_sizes, int n_in,
                              void* d_out, int out_size, void* d_ws, size_t ws_size,
                              hipStream_t stream) {
    float* out = (float*)d_out;   // reference output dtype is float32

    static const int expected[18] = {
        NN * DIN, DIN, DIN, DIN * HID, HID, DIN * HID, HID, HID, HID,
        HID, HID, HID * NH, NH, HID * NH, NH, NH, 1, 2 * E0
    };
    if (n_in != 18) {
        debug_fill<<<(NN + 255) / 256, 256, 0, stream>>>(out, 8192.f + 64.f * (float)n_in);
        return;
    }
    for (int i = 0; i < 18; ++i) {
        if (in_sizes[i] != expected[i]) {
            debug_fill<<<(NN + 255) / 256, 256, 0, stream>>>(out, 4096.f + 32.f * (float)i);
            return;
        }
    }

    const float* x      = (const float*)d_in[0];
    const float* gamma1 = (const float*)d_in[1];
    const float* beta1  = (const float*)d_in[2];
    const float* Wl1    = (const float*)d_in[3];
    const float* bl1    = (const float*)d_in[4];
    const float* Wr1    = (const float*)d_in[5];
    const float* br1    = (const float*)d_in[6];
    const float* att1   = (const float*)d_in[7];
    const float* bias1  = (const float*)d_in[8];
    const float* gamma2 = (const float*)d_in[9];
    const float* beta2  = (const float*)d_in[10];
    const float* Wl2    = (const float*)d_in[11];
    const float* bl2    = (const float*)d_in[12];
    const float* Wr2    = (const float*)d_in[13];
    const float* br2    = (const float*)d_in[14];
    const float* att2   = (const float*)d_in[15];
    const float* bias2  = (const float*)d_in[16];
    const int*   ei     = (const int*)d_in[17];

    char* p = (char*)d_ws;
    auto alloc = [&](size_t bytes) -> void* {
        void* r = (void*)p;
        p += (bytes + 255) & ~(size_t)255;
        return r;
    };
    unsigned short* xl1  = (unsigned short*)alloc((size_t)NN * HID * 2);  // 20.48 MB
    unsigned short* xr1  = (unsigned short*)alloc((size_t)NN * HID * 2);  // 20.48 MB
    unsigned short* agg  = xr1;                                           // ALIAS (see gat1_node)
    unsigned short* hn   = (unsigned short*)alloc((size_t)NN * KP * 2);   // 3.84 MB
    unsigned short* wlt  = (unsigned short*)alloc((size_t)HID * KP * 2);  // 0.39 MB
    unsigned short* wrt  = (unsigned short*)alloc((size_t)HID * KP * 2);  // 0.39 MB
    float*          xl2  = (float*)alloc((size_t)NN * 8 * 4);
    float*          xr2  = (float*)alloc((size_t)NN * 8 * 4);
    int*            offs = (int*)alloc((NN + 1) * 4);
    int*            cur  = (int*)alloc(NN * 4);
    int*            ssrc = (int*)alloc(ET * 4);
    int*            perm = (int*)alloc(NN * 4);
    char* zbase = p;
    float* colsum1 = (float*)alloc(DIN * 4);
    float* colsq1  = (float*)alloc(DIN * 4);
    float* colsum2 = (float*)alloc(HID * 4);
    float* colsq2  = (float*)alloc(HID * 4);
    int*   deg     = (int*)alloc(NN * 4);
    size_t zlen = (size_t)(p - zbase);
    hipMemsetAsync(zbase, 0, zlen, stream);

    // 8 dispatches (r20: gemm1 redesigned 64x128/2512-block; rest = r19)
    fuseA_kernel<<<125 + (ET + 255) / 256, 256, 0, stream>>>(x, colsum1, colsq1, ei, deg);
    fuseB_kernel<<<1 + (NN * KP + 1023) / 1024, 1024, 0, stream>>>(
        deg, offs, cur, perm, x, colsum1, colsq1, gamma1, beta1, hn);
    fuseC_kernel<<<192 + (ET + 255) / 256, 256, 0, stream>>>(Wl1, Wr1, wlt, wrt, ei, cur, ssrc);
    gemm1_kernel<<<dim3((NN + 63) / 64, 16), 256, 0, stream>>>(hn, wlt, wrt, bl1, br1, xl1, xr1);
    gat1_node<<<NN / 4, 256, 0, stream>>>(xl1, xr1, att1, bias1, offs, ssrc, perm, agg);
    bn2_stats<<<125, 256, 0, stream>>>(agg, colsum2, colsq2);
    gemm2_kernel<<<NN / 16, 256, 0, stream>>>(agg, colsum2, colsq2, gamma2, beta2,
                                              Wl2, Wr2, bl2, br2, xl2, xr2);
    gat2_node<<<NN / 4, 256, 0, stream>>>(xl2, xr2, att2, bias2, offs, ssrc, perm, out);
}